// Round 23
// baseline (31.176 us; speedup 1.0000x reference)
//
#include <hip/hip_runtime.h>
#include <float.h>

#define NB 68                 // padded bins (64 + 2*2)
#define NJ (NB * NB)          // 4624 joint bins
#define NSLICE 4              // J slices (flush chain depth ~31)
#define TPB 1024
#define BXB 125               // blocks per batch; 250 total <= 256 CUs ->
                              // all co-resident -> spin-wait is deadlock-free
#define SCALE 16384.0f        // 2^14: batch bin total <= 3.7e9 < 2^32 -> u32 J
#define LHSZ (2 * NJ + 8)     // two LDS copies + shift pad
#define ZWORDS ((NSLICE * NJ + BXB - 1) / BXB)   // 148 J-words zeroed per block

// ws layout (bytes):
// [0 .. 16)            ctr[4]: phase1 tickets (b=0,1), phase2 tickets (b=0,1)
// [64 .. 64+2*128*16)  P: minmax partials as u32x4 {smx,smn,tmx,tmn}
// [4160 .. +NSLICE*2*NJ*4)  J: u32 joint totals [slice][b][NJ]

__device__ __forceinline__ float bspl(float d) {
    float ad = fabsf(d);
    float a = (3.0f * ad * ad * ad - 6.0f * ad * ad + 4.0f) * (1.0f / 6.0f);
    float t = 2.0f - ad;
    float c = t * t * t * (1.0f / 6.0f);
    return ad < 1.0f ? a : (ad < 2.0f ? c : 0.0f);
}

// Packed-u64 tap deposit (8 ds_add_u64/voxel); copy by ti parity keeps the
// u64 pair 8-byte aligned. Low-lane carry impossible (per-copy per-bin
// <= 4096*0.444*16384 = 3e7 << 2^32).
__device__ __forceinline__ void vox1(float sv, float tv, unsigned* lh,
                                     float spad, float sinv, float tpad,
                                     float tinv) {
    float posS = (sv - spad) * sinv;
    float fS = floorf(posS);
    fS = fminf(fmaxf(fS, 2.0f), 65.0f);
    int si = (int)fS - 1;
    float dS = posS - fS;
    float a[4] = {bspl(dS + 1.0f), bspl(dS), bspl(dS - 1.0f), bspl(dS - 2.0f)};

    float posT = (tv - tpad) * tinv;
    float fT = floorf(posT);
    fT = fminf(fmaxf(fT, 2.0f), 65.0f);
    int ti = (int)fT - 1;
    float dT = posT - fT;
    float b0 = bspl(dT + 1.0f), b1 = bspl(dT), b2 = bspl(dT - 1.0f),
          b3 = bspl(dT - 2.0f);

    unsigned* base = lh + ((ti & 1) ? (NJ + 1) : 0) + si * NB + ti;
#pragma unroll
    for (int r = 0; r < 4; ++r) {
        unsigned q0 = (unsigned)(a[r] * b0 * SCALE + 0.5f);
        unsigned q1 = (unsigned)(a[r] * b1 * SCALE + 0.5f);
        unsigned q2 = (unsigned)(a[r] * b2 * SCALE + 0.5f);
        unsigned q3 = (unsigned)(a[r] * b3 * SCALE + 0.5f);
        atomicAdd((unsigned long long*)(base + r * NB),
                  (unsigned long long)q0 | ((unsigned long long)q1 << 32));
        atomicAdd((unsigned long long*)(base + r * NB + 2),
                  (unsigned long long)q2 | ((unsigned long long)q3 << 32));
    }
}

// Single persistent kernel. Voxels read ONCE into registers. Cross-block
// comms exclusively via device-scope atomics at the coherence point
// (agent-scope stores/loads + release tickets after vmcnt-draining
// barriers) -- the r22-validated pattern; NO threadfence, NO grid.sync
// (r7/r8's regressions were those primitives' bulk L2 machinery).
__global__ __launch_bounds__(TPB) void k_all(
    const float* __restrict__ src, const float* __restrict__ tgt,
    unsigned* __restrict__ P, unsigned* __restrict__ J,
    unsigned* __restrict__ ctr, float* __restrict__ out, double inv, int n4) {
    __shared__ __align__(16) unsigned lh[LHSZ];
    __shared__ float red[16][4];
    __shared__ float pmm[8], mmv[4];
    __shared__ unsigned lastFlag;
    const int tid = threadIdx.x, bx = blockIdx.x, b = blockIdx.y;

    // ---- phase 0: load voxels (registers), zero LDS, zero J share ----
    const int i0 = bx * TPB + tid;
    const bool valid = i0 < n4;              // exact for 80^3: 125*1024==n4
    float4 sv = make_float4(0.f, 0.f, 0.f, 0.f);
    float4 tv = make_float4(0.f, 0.f, 0.f, 0.f);
    if (valid) {
        sv = ((const float4*)src)[(size_t)b * n4 + i0];
        tv = ((const float4*)tgt)[(size_t)b * n4 + i0];
    }
    uint4* z4 = (uint4*)lh;
    const uint4 zz = make_uint4(0u, 0u, 0u, 0u);
    for (int i = tid; i < LHSZ / 4; i += TPB) z4[i] = zz;
    if (tid < ZWORDS) {
        int g = bx * ZWORDS + tid;
        if (g < NSLICE * NJ) {
            int sl = g / NJ, i = g - sl * NJ;
            __hip_atomic_store(&J[((size_t)sl * 2 + b) * NJ + i], 0u,
                               __ATOMIC_RELAXED, __HIP_MEMORY_SCOPE_AGENT);
        }
    }

    // ---- phase 1: block minmax partial ----
    float smx = -FLT_MAX, smn = FLT_MAX, tmx = -FLT_MAX, tmn = FLT_MAX;
    if (valid) {
        smx = fmaxf(fmaxf(sv.x, sv.y), fmaxf(sv.z, sv.w));
        smn = fminf(fminf(sv.x, sv.y), fminf(sv.z, sv.w));
        tmx = fmaxf(fmaxf(tv.x, tv.y), fmaxf(tv.z, tv.w));
        tmn = fminf(fminf(tv.x, tv.y), fminf(tv.z, tv.w));
    }
#pragma unroll
    for (int m = 1; m < 64; m <<= 1) {
        smx = fmaxf(smx, __shfl_xor(smx, m));
        smn = fminf(smn, __shfl_xor(smn, m));
        tmx = fmaxf(tmx, __shfl_xor(tmx, m));
        tmn = fminf(tmn, __shfl_xor(tmn, m));
    }
    const int wave = tid >> 6;
    if ((tid & 63) == 0) {
        red[wave][0] = smx;
        red[wave][1] = smn;
        red[wave][2] = tmx;
        red[wave][3] = tmn;
    }
    __syncthreads();   // drains vmcnt: J-zero stores + LDS zero complete

    if (tid == 0) {
#pragma unroll
        for (int k = 1; k < 16; ++k) {
            smx = fmaxf(smx, red[k][0]);
            smn = fminf(smn, red[k][1]);
            tmx = fmaxf(tmx, red[k][2]);
            tmn = fminf(tmn, red[k][3]);
        }
        const unsigned pb = (unsigned)(b * 128 + bx) * 4u;
        __hip_atomic_store(&P[pb + 0], __float_as_uint(smx), __ATOMIC_RELAXED,
                           __HIP_MEMORY_SCOPE_AGENT);
        __hip_atomic_store(&P[pb + 1], __float_as_uint(smn), __ATOMIC_RELAXED,
                           __HIP_MEMORY_SCOPE_AGENT);
        __hip_atomic_store(&P[pb + 2], __float_as_uint(tmx), __ATOMIC_RELAXED,
                           __HIP_MEMORY_SCOPE_AGENT);
        __hip_atomic_store(&P[pb + 3], __float_as_uint(tmn), __ATOMIC_RELAXED,
                           __HIP_MEMORY_SCOPE_AGENT);
        __hip_atomic_fetch_add(&ctr[b], 1u, __ATOMIC_RELEASE,
                               __HIP_MEMORY_SCOPE_AGENT);
        while (__hip_atomic_load(&ctr[b], __ATOMIC_RELAXED,
                                 __HIP_MEMORY_SCOPE_AGENT) < (unsigned)BXB) {
        }
    }
    __syncthreads();

    // ---- inline reduce of the 125 partials (2 waves, agent loads) ----
    if (tid < 128) {
        float a = -FLT_MAX, c = FLT_MAX, d = -FLT_MAX, e = FLT_MAX;
        if (tid < BXB) {
            const unsigned pb = (unsigned)(b * 128 + tid) * 4u;
            a = __uint_as_float(__hip_atomic_load(&P[pb + 0], __ATOMIC_RELAXED,
                                                  __HIP_MEMORY_SCOPE_AGENT));
            c = __uint_as_float(__hip_atomic_load(&P[pb + 1], __ATOMIC_RELAXED,
                                                  __HIP_MEMORY_SCOPE_AGENT));
            d = __uint_as_float(__hip_atomic_load(&P[pb + 2], __ATOMIC_RELAXED,
                                                  __HIP_MEMORY_SCOPE_AGENT));
            e = __uint_as_float(__hip_atomic_load(&P[pb + 3], __ATOMIC_RELAXED,
                                                  __HIP_MEMORY_SCOPE_AGENT));
        }
#pragma unroll
        for (int m = 1; m < 64; m <<= 1) {
            a = fmaxf(a, __shfl_xor(a, m));
            c = fminf(c, __shfl_xor(c, m));
            d = fmaxf(d, __shfl_xor(d, m));
            e = fminf(e, __shfl_xor(e, m));
        }
        if ((tid & 63) == 0) {
            int w = tid >> 6;
            pmm[w * 4 + 0] = a;
            pmm[w * 4 + 1] = c;
            pmm[w * 4 + 2] = d;
            pmm[w * 4 + 3] = e;
        }
    }
    __syncthreads();
    if (tid == 0) {
        mmv[0] = fmaxf(pmm[0], pmm[4]);
        mmv[1] = fminf(pmm[1], pmm[5]);
        mmv[2] = fmaxf(pmm[2], pmm[6]);
        mmv[3] = fminf(pmm[3], pmm[7]);
    }
    __syncthreads();

    // ---- phase 2: LDS hist from register-cached voxels ----
    const float sbw = (mmv[0] - mmv[1]) * (1.0f / 64.0f);
    const float tbw = (mmv[2] - mmv[3]) * (1.0f / 64.0f);
    const float sinv = 1.0f / sbw, tinv = 1.0f / tbw;
    const float spad = mmv[1] - 2.0f * sbw;
    const float tpad = mmv[3] - 2.0f * tbw;

    if (valid) {
        vox1(sv.x, tv.x, lh, spad, sinv, tpad, tinv);
        vox1(sv.y, tv.y, lh, spad, sinv, tpad, tinv);
        vox1(sv.z, tv.z, lh, spad, sinv, tpad, tinv);
        vox1(sv.w, tv.w, lh, spad, sinv, tpad, tinv);
    }
    __syncthreads();

    // rotated, sliced u32 flush
    const int rot = (bx * 1327) % NJ;
    unsigned* Jb = J + ((size_t)(bx & (NSLICE - 1)) * 2 + b) * NJ;
    for (int k = tid; k < NJ; k += TPB) {
        int i = k + rot;
        if (i >= NJ) i -= NJ;
        unsigned s = lh[i] + lh[NJ + 1 + i];
        if (s) atomicAdd(&Jb[i], s);
    }
    __syncthreads();   // drains vmcnt: this block's flush atomics acked

    if (tid == 0)
        lastFlag = (__hip_atomic_fetch_add(&ctr[2 + b], 1u, __ATOMIC_RELEASE,
                                           __HIP_MEMORY_SCOPE_AGENT) ==
                    (unsigned)(BXB - 1))
                       ? 1u
                       : 0u;
    __syncthreads();
    if (!lastFlag) return;

    // ---- last block of batch b: finalize (reuse lh as float scratch) ----
    float* jf = (float*)lh;                  // NJ floats
    float* part = (float*)(lh + NJ + 16);    // [NB][8]
    for (int i = tid; i < NJ; i += TPB) {
        unsigned s = 0u;
#pragma unroll
        for (int sl = 0; sl < NSLICE; ++sl)
            s += __hip_atomic_load(&J[((size_t)sl * 2 + b) * NJ + i],
                                   __ATOMIC_RELAXED, __HIP_MEMORY_SCOPE_AGENT);
        float f = (float)((double)s * inv);
        jf[i] = f;
        out[4 * NB + b * NJ + i] = f;
    }
    __syncthreads();

    if (tid < 8 * NB) {                      // rows: 8 partials per row
        int r = tid >> 3, k = tid & 7;
        float s = 0.0f;
#pragma unroll
        for (int j = 0; j < 9; ++j) {
            int c = k + 8 * j;
            if (c < NB) s += jf[r * NB + c];
        }
        part[r * 8 + k] = s;
    }
    __syncthreads();
    if (tid < NB) {
        float s = part[tid * 8 + 0] + part[tid * 8 + 1] + part[tid * 8 + 2] +
                  part[tid * 8 + 3] + part[tid * 8 + 4] + part[tid * 8 + 5] +
                  part[tid * 8 + 6] + part[tid * 8 + 7];
        out[b * NB + tid] = s;
    }
    __syncthreads();

    if (tid < 8 * NB) {                      // cols: 8 partials per col
        int c = tid >> 3, k = tid & 7;
        float s = 0.0f;
#pragma unroll
        for (int j = 0; j < 9; ++j) {
            int r = k + 8 * j;
            if (r < NB) s += jf[r * NB + c];
        }
        part[c * 8 + k] = s;
    }
    __syncthreads();
    if (tid < NB) {
        float s = part[tid * 8 + 0] + part[tid * 8 + 1] + part[tid * 8 + 2] +
                  part[tid * 8 + 3] + part[tid * 8 + 4] + part[tid * 8 + 5] +
                  part[tid * 8 + 6] + part[tid * 8 + 7];
        out[2 * NB + b * NB + tid] = s;
    }
}

extern "C" void kernel_launch(void* const* d_in, const int* in_sizes, int n_in,
                              void* d_out, int out_size, void* d_ws,
                              size_t ws_size, hipStream_t stream) {
    const float* src = (const float*)d_in[0];
    const float* tgt = (const float*)d_in[1];
    float* out = (float*)d_out;
    unsigned* ctr = (unsigned*)d_ws;
    unsigned* P = (unsigned*)((char*)d_ws + 64);
    unsigned* J = (unsigned*)((char*)d_ws + 4160);
    const int nvox = in_sizes[0] / 2;              // 512000
    const int n4 = nvox / 4;                       // 128000
    const double inv = 1.0 / ((double)nvox * (double)SCALE);

    hipMemsetAsync(ctr, 0, 16, stream);            // graph-capturable memset
    k_all<<<dim3(BXB, 2), dim3(TPB), 0, stream>>>(src, tgt, P, J, ctr, out,
                                                  inv, n4);
}

// Round 24
// 22.364 us; speedup vs baseline: 1.3940x; 1.3940x over previous
//
#include <hip/hip_runtime.h>
#include <float.h>

#define NB 68                 // padded bins (64 + 2*2)
#define NJ (NB * NB)          // 4624 joint bins
#define NSLICE 4              // J slices (flush chain depth ~31; r17 optimum)
#define HTPB 1024             // k_hist threads per block
#define MMBLK 125             // blocks per batch (125*1024 = 128000 float4s)
#define SCALE 16384.0f        // 2^14: worst-case one-bin batch total
                              // 512000*0.444*16384 = 3.7e9 < 2^32 -> u32 J
#define LHSZ (2 * NJ + 8)     // two copies + 1-word shift pad + alignment

// ws layout (bytes):
// [64 .. 64+2*128*16)  P: per-block minmax partials, float4 {smx,smn,tmx,tmn}
// [4160 .. +NSLICE*2*NJ*4)  J: u32 joint totals [slice][b][NJ]

// Kernel 1: minmax block partials + zero J slices. One float4 of src+tgt
// per thread (all loads in flight), block reduce, one plain float4 store.
__global__ __launch_bounds__(1024) void k_prep(const float* __restrict__ src,
                                               const float* __restrict__ tgt,
                                               float4* __restrict__ P,
                                               unsigned* __restrict__ J,
                                               int n4) {
    __shared__ float red[16][4];
    const int b = blockIdx.y;
    const int lin = (b * gridDim.x + blockIdx.x) * 1024 + threadIdx.x;
    if (lin < NSLICE * 2 * NJ) J[lin] = 0u;

    const int i = blockIdx.x * 1024 + threadIdx.x;
    float smx = -FLT_MAX, smn = FLT_MAX, tmx = -FLT_MAX, tmn = FLT_MAX;
    if (i < n4) {
        float4 v = ((const float4*)src)[(size_t)b * n4 + i];
        float4 w = ((const float4*)tgt)[(size_t)b * n4 + i];
        smx = fmaxf(fmaxf(v.x, v.y), fmaxf(v.z, v.w));
        smn = fminf(fminf(v.x, v.y), fminf(v.z, v.w));
        tmx = fmaxf(fmaxf(w.x, w.y), fmaxf(w.z, w.w));
        tmn = fminf(fminf(w.x, w.y), fminf(w.z, w.w));
    }
#pragma unroll
    for (int m = 1; m < 64; m <<= 1) {
        smx = fmaxf(smx, __shfl_xor(smx, m));
        smn = fminf(smn, __shfl_xor(smn, m));
        tmx = fmaxf(tmx, __shfl_xor(tmx, m));
        tmn = fminf(tmn, __shfl_xor(tmn, m));
    }
    const int wave = threadIdx.x >> 6;
    if ((threadIdx.x & 63) == 0) {
        red[wave][0] = smx;
        red[wave][1] = smn;
        red[wave][2] = tmx;
        red[wave][3] = tmn;
    }
    __syncthreads();
    if (threadIdx.x == 0) {
#pragma unroll
        for (int k = 1; k < 16; ++k) {
            smx = fmaxf(smx, red[k][0]);
            smn = fminf(smn, red[k][1]);
            tmx = fmaxf(tmx, red[k][2]);
            tmn = fminf(tmn, red[k][3]);
        }
        P[b * 128 + blockIdx.x] = make_float4(smx, smn, tmx, tmn);
    }
}

__device__ __forceinline__ float bspl(float d) {
    float ad = fabsf(d);
    float a = (3.0f * ad * ad * ad - 6.0f * ad * ad + 4.0f) * (1.0f / 6.0f);
    float t = 2.0f - ad;
    float c = t * t * t * (1.0f / 6.0f);
    return ad < 1.0f ? a : (ad < 2.0f ? c : 0.0f);
}

// Packed-u64 tap deposit: 8 ds_add_u64 per voxel (was 16 ds_add_u32).
// Copy chosen by ti parity so the u64 pair boundary is 8-byte aligned:
// copy0 = lh[0..), normal layout; copy1 = lh[NJ+1..), shifted one u32.
// Low-lane carry impossible: per-copy per-bin <= 4096*0.444*16384 = 3e7.
__device__ __forceinline__ void vox1(float sv, float tv, unsigned* lh,
                                     float spad, float sinv, float tpad,
                                     float tinv) {
    float posS = (sv - spad) * sinv;
    float fS = floorf(posS);
    fS = fminf(fmaxf(fS, 2.0f), 65.0f);
    int si = (int)fS - 1;
    float dS = posS - fS;
    float a[4] = {bspl(dS + 1.0f), bspl(dS), bspl(dS - 1.0f), bspl(dS - 2.0f)};

    float posT = (tv - tpad) * tinv;
    float fT = floorf(posT);
    fT = fminf(fmaxf(fT, 2.0f), 65.0f);
    int ti = (int)fT - 1;
    float dT = posT - fT;
    float b0 = bspl(dT + 1.0f), b1 = bspl(dT), b2 = bspl(dT - 1.0f),
          b3 = bspl(dT - 2.0f);

    unsigned* base = lh + ((ti & 1) ? (NJ + 1) : 0) + si * NB + ti;
#pragma unroll
    for (int r = 0; r < 4; ++r) {
        unsigned q0 = (unsigned)(a[r] * b0 * SCALE + 0.5f);
        unsigned q1 = (unsigned)(a[r] * b1 * SCALE + 0.5f);
        unsigned q2 = (unsigned)(a[r] * b2 * SCALE + 0.5f);
        unsigned q3 = (unsigned)(a[r] * b3 * SCALE + 0.5f);
        atomicAdd((unsigned long long*)(base + r * NB),
                  (unsigned long long)q0 | ((unsigned long long)q1 << 32));
        atomicAdd((unsigned long long*)(base + r * NB + 2),
                  (unsigned long long)q2 | ((unsigned long long)q3 << 32));
    }
}

// Kernel 2: 1024 threads/block, 125 blocks/batch (1 float4/thread,
// 16 waves/CU). LDS u32 hist, 2 parity-selected copies, packed u64
// deposits. u32 atomic flush into slice (bx & 3) with per-block rotation.
// Integer -> deterministic.
__global__ __launch_bounds__(HTPB) void k_hist(
    const float* __restrict__ src, const float* __restrict__ tgt,
    const float4* __restrict__ P, unsigned* __restrict__ J, int n4) {
    __shared__ __align__(16) unsigned lh[LHSZ];
    __shared__ float pmm[8], mmv[4];
    const int tid = threadIdx.x;
    const int b = blockIdx.y;

    // inline reduce of the 125 minmax partials (2 waves)
    if (tid < 128) {
        float smx = -FLT_MAX, smn = FLT_MAX, tmx = -FLT_MAX, tmn = FLT_MAX;
        if (tid < MMBLK) {
            float4 v = P[b * 128 + tid];
            smx = v.x; smn = v.y; tmx = v.z; tmn = v.w;
        }
#pragma unroll
        for (int m = 1; m < 64; m <<= 1) {
            smx = fmaxf(smx, __shfl_xor(smx, m));
            smn = fminf(smn, __shfl_xor(smn, m));
            tmx = fmaxf(tmx, __shfl_xor(tmx, m));
            tmn = fminf(tmn, __shfl_xor(tmn, m));
        }
        if ((tid & 63) == 0) {
            int w = tid >> 6;
            pmm[w * 4 + 0] = smx;
            pmm[w * 4 + 1] = smn;
            pmm[w * 4 + 2] = tmx;
            pmm[w * 4 + 3] = tmn;
        }
    }
    // zero LDS hist concurrently
    uint4* z4 = (uint4*)lh;
    const uint4 zz = make_uint4(0u, 0u, 0u, 0u);
    for (int i = tid; i < LHSZ / 4; i += HTPB) z4[i] = zz;
    __syncthreads();
    if (tid == 0) {
        mmv[0] = fmaxf(pmm[0], pmm[4]);   // smx
        mmv[1] = fminf(pmm[1], pmm[5]);   // smn
        mmv[2] = fmaxf(pmm[2], pmm[6]);   // tmx
        mmv[3] = fminf(pmm[3], pmm[7]);   // tmn
    }
    __syncthreads();

    const float sbw = (mmv[0] - mmv[1]) * (1.0f / 64.0f);
    const float tbw = (mmv[2] - mmv[3]) * (1.0f / 64.0f);
    const float sinv = 1.0f / sbw, tinv = 1.0f / tbw;
    const float spad = mmv[1] - 2.0f * sbw;
    const float tpad = mmv[3] - 2.0f * tbw;

    const int i0 = blockIdx.x * HTPB + tid;
    if (i0 < n4) {
        float4 sA = ((const float4*)src)[(size_t)b * n4 + i0];
        float4 tA = ((const float4*)tgt)[(size_t)b * n4 + i0];
        vox1(sA.x, tA.x, lh, spad, sinv, tpad, tinv);
        vox1(sA.y, tA.y, lh, spad, sinv, tpad, tinv);
        vox1(sA.z, tA.z, lh, spad, sinv, tpad, tinv);
        vox1(sA.w, tA.w, lh, spad, sinv, tpad, tinv);
    }
    __syncthreads();

    // rotated, sliced flush (u32): copy1 logical bin i at lh[NJ+1+i]
    const int rot = (blockIdx.x * 1327) % NJ;
    unsigned* Jb = J + ((size_t)(blockIdx.x & (NSLICE - 1)) * 2 + b) * NJ;
    for (int k = tid; k < NJ; k += HTPB) {
        int i = k + rot;
        if (i >= NJ) i -= NJ;
        unsigned s = lh[i] + lh[NJ + 1 + i];
        if (s) atomicAdd(&Jb[i], s);
    }
}

// Kernel 3: one 1024-thread block per batch. Sum the 4 u32 J slices while
// staging into LDS (emitting joint density), then row/col sums as 8-way
// parallel partials over LDS. Analytic total nvox*2^14.
__global__ __launch_bounds__(1024) void k_norm(
    const unsigned* __restrict__ J, float* __restrict__ out, double inv) {
    __shared__ float jf[NJ];
    __shared__ float part[NB][8];
    const int b = blockIdx.x;
    const int tid = threadIdx.x;

    for (int i = tid; i < NJ; i += 1024) {
        unsigned s = 0u;                      // batch total per bin < 2^32
#pragma unroll
        for (int sl = 0; sl < NSLICE; ++sl)
            s += J[((size_t)sl * 2 + b) * NJ + i];
        float f = (float)((double)s * inv);
        jf[i] = f;
        out[4 * NB + b * NJ + i] = f;
    }
    __syncthreads();

    if (tid < 8 * NB) {                       // rows: 8 partials per row
        int r = tid >> 3, k = tid & 7;
        float s = 0.0f;
#pragma unroll
        for (int j = 0; j < 9; ++j) {
            int c = k + 8 * j;
            if (c < NB) s += jf[r * NB + c];
        }
        part[r][k] = s;
    }
    __syncthreads();
    if (tid < NB) {
        float s = part[tid][0] + part[tid][1] + part[tid][2] + part[tid][3] +
                  part[tid][4] + part[tid][5] + part[tid][6] + part[tid][7];
        out[b * NB + tid] = s;
    }
    __syncthreads();

    if (tid < 8 * NB) {                       // cols: 8 partials per col
        int c = tid >> 3, k = tid & 7;
        float s = 0.0f;
#pragma unroll
        for (int j = 0; j < 9; ++j) {
            int r = k + 8 * j;
            if (r < NB) s += jf[r * NB + c];
        }
        part[c][k] = s;
    }
    __syncthreads();
    if (tid < NB) {
        float s = part[tid][0] + part[tid][1] + part[tid][2] + part[tid][3] +
                  part[tid][4] + part[tid][5] + part[tid][6] + part[tid][7];
        out[2 * NB + b * NB + tid] = s;
    }
}

extern "C" void kernel_launch(void* const* d_in, const int* in_sizes, int n_in,
                              void* d_out, int out_size, void* d_ws,
                              size_t ws_size, hipStream_t stream) {
    const float* src = (const float*)d_in[0];
    const float* tgt = (const float*)d_in[1];
    float* out = (float*)d_out;
    float4* P = (float4*)((char*)d_ws + 64);
    unsigned* J = (unsigned*)((char*)d_ws + 4160);
    const int nvox = in_sizes[0] / 2;              // 512000
    const int n4 = nvox / 4;                       // 128000
    const double inv = 1.0 / ((double)nvox * (double)SCALE);

    k_prep<<<dim3(MMBLK, 2), dim3(1024), 0, stream>>>(src, tgt, P, J, n4);
    k_hist<<<dim3(MMBLK, 2), dim3(HTPB), 0, stream>>>(src, tgt, P, J, n4);
    k_norm<<<dim3(2), dim3(1024), 0, stream>>>(J, out, inv);
}